// Round 19
// baseline (80.603 us; speedup 1.0000x reference)
//
#include <hip/hip_runtime.h>
#include <hip/hip_bf16.h>
#include <math.h>

#define B_  8
#define C_  128
#define CH_ 64
#define LX_ 128
#define LY_ 1024

typedef __attribute__((ext_vector_type(8)))  _Float16 half8;
typedef __attribute__((ext_vector_type(16))) float f32x16;

// ---------------- K1: att = x^T @ W + b -> fp16 (LDS-FREE: x via scalar loads) ----
// x[b][c][l0..l0+3] is thread-uniform -> compiler emits s_load_dwordx4 per c
// (scalar/K$ pipe). No LDS, no barrier. Blocks 0..63 also prep wdTh.
__global__ __launch_bounds__(128) void k1_att(
    const float* __restrict__ x, const float* __restrict__ y,
    const float* __restrict__ Wd, const float* __restrict__ bd,
    const float* __restrict__ Wp, const float* __restrict__ bp,
    const float* __restrict__ Wdown,
    _Float16* __restrict__ datt, _Float16* __restrict__ patt,
    _Float16* __restrict__ wdTh)
{
    const int blk = blockIdx.x;
    const int t = threadIdx.x;
    if (blk < 64) {                        // wdTh[kh][c] = (fp16) W_down[c][kh]
        int u = blk * 128 + t;
        wdTh[u] = (_Float16)Wdown[(u & 127) * CH_ + (u >> 7)];
    }
    const float* src; const float* W; const float* bias; _Float16* dst; int L;
    int b, l0;
    if (blk < 256) {
        int row0 = blk * 4; b = row0 >> 7; l0 = row0 & 127;
        src = x; W = Wd; bias = bd; dst = datt; L = LX_;
    } else {
        int row0 = (blk - 256) * 4; b = row0 >> 10; l0 = row0 & 1023;
        src = y; W = Wp; bias = bp; dst = patt; L = LY_;
    }
    const float* xrow = src + (long)b * C_ * L + l0;   // x[b][c][l0+i] = xrow[c*L+i]
    float acc0 = bias[t], acc1 = acc0, acc2 = acc0, acc3 = acc0;
    #pragma unroll 8
    for (int c = 0; c < 128; ++c) {
        float w = W[c * 128 + t];                      // vector load, L2-hot
        const float* sp = xrow + (long)c * L;          // uniform -> s_load_dwordx4
        float s0 = sp[0], s1 = sp[1], s2 = sp[2], s3 = sp[3];
        acc0 = fmaf(s0, w, acc0); acc1 = fmaf(s1, w, acc1);
        acc2 = fmaf(s2, w, acc2); acc3 = fmaf(s3, w, acc3);
    }
    _Float16* dp = dst + ((long)b * L + l0) * C_ + t;
    dp[0]      = (_Float16)acc0; dp[C_]     = (_Float16)acc1;
    dp[2 * C_] = (_Float16)acc2; dp[3 * C_] = (_Float16)acc3;
}

// ---------------- K2: R18's MFMA loop; Hx partials DIRECT to global (no compWp) ---
// grid 1024, LB(256,4), LDS = 8.7 KB d-tile only. Per-row Hx h-partial stored
// straight to fp16 slab (64 slabs = lyblk x h) on the idle VMEM pipe; kills the
// per-row ds_write, the 17 KB LDS buffer, the 2nd barrier, and the epilogue.
__global__ __launch_bounds__(256, 4) void k2_main(
    const _Float16* __restrict__ datt, const _Float16* __restrict__ patt,
    const _Float16* __restrict__ wdTh, const float* __restrict__ bdown,
    _Float16* __restrict__ HxPh, _Float16* __restrict__ HyPh)
{
    const int raw = blockIdx.x;
    const int bid = (raw & 7) * 128 + (raw >> 3);   // XCD-contiguous: share d-tiles
    const int lyblk = bid & 31;
    const int lxblk = (bid >> 5) & 3;
    const int b     = bid >> 7;
    const int t   = threadIdx.x;
    const int w   = t >> 6;
    const int wk  = w >> 1;             // kh half
    const int wl  = w & 1;              // lx half
    const int l   = t & 63;
    const int h   = l >> 5;             // k subgroup
    const int c32 = l & 31;             // ly row for A/pv; kh col for B/D

    __shared__ _Float16 dTh[32][136];     // 8.7 KB d-tile

    // ---- stage d-tile (coalesced: 512 half8 groups, contiguous) ----
    {
        const _Float16* dsrc = datt + ((long)(b * LX_) + lxblk * 32) * C_;
        #pragma unroll
        for (int i = 0; i < 2; ++i) {
            int idx = t + i * 256;
            *(half8*)&dTh[idx >> 4][(idx & 15) * 8] = *(const half8*)(dsrc + idx * 8);
        }
    }

    // ---- hoist p-fragments and B-fragments ----
    const _Float16* prow = patt + ((long)(b * LY_) + lyblk * 32 + c32) * C_ + h * 8;
    const _Float16* wrow = wdTh + (wk * 32 + c32) * C_ + h * 8;
    half8 pv[8], bf[8];
    #pragma unroll
    for (int kt = 0; kt < 8; ++kt) {
        pv[kt] = *(const half8*)(prow + kt * 16);
        bf[kt] = *(const half8*)(wrow + kt * 16);
    }
    const float bdr = bdown[wk * 32 + c32];
    const half8 hz = {};
    __syncthreads();

    // per-row Hx destination: slab (lyblk*2 + h), row (lxblk*32 + wl*16 + r)
    _Float16* hxp = HxPh
        + (((long)(lyblk * 2 + h) * B_ + b) * LX_ + lxblk * 32 + wl * 16) * 64
        + wk * 32 + c32;

    float hy[16];
    #pragma unroll
    for (int r = 0; r < 16; ++r) hy[r] = 0.f;

    #pragma unroll 1
    for (int r = 0; r < 16; ++r) {
        const _Float16* dp = &dTh[wl * 16 + r][h * 8];
        f32x16 acc = {};
        #pragma unroll
        for (int kt = 0; kt < 8; ++kt) {
            half8 d = *(const half8*)(dp + kt * 16);            // LDS broadcast
            half8 s = __builtin_elementwise_max(d + pv[kt], hz);
            acc = __builtin_amdgcn_mfma_f32_32x32x16_f16(s, bf[kt], acc, 0, 0, 0);
        }
        // readout. D: col(kh)=wk*32+c32, row(ly)=(rr&3)+8*(rr>>2)+4h ; bias here
        float pa0 = 0.f, pa1 = 0.f, pa2 = 0.f, pa3 = 0.f;
        #pragma unroll
        for (int rr = 0; rr < 16; ++rr) {
            float v = fmaxf(acc[rr] + bdr, 0.f);
            hy[rr] += v;
            if      ((rr & 3) == 0) pa0 += v;
            else if ((rr & 3) == 1) pa1 += v;
            else if ((rr & 3) == 2) pa2 += v;
            else                    pa3 += v;
        }
        hxp[(long)r * 64] = (_Float16)((pa0 + pa1) + (pa2 + pa3));  // VMEM pipe
    }

    // ---- Hy -> exclusive fp16 slab (lxblk*2+wl), plain stores ----
    {
        _Float16* hyp = HyPh
            + (((long)(lxblk * 2 + wl) * B_ + b) * LY_ + lyblk * 32) * 64
            + wk * 32 + c32;
        #pragma unroll
        for (int rr = 0; rr < 16; ++rr) {
            int ly = (rr & 3) + 8 * (rr >> 2) + 4 * h;
            hyp[(long)ly * 64] = (_Float16)hy[rr];
        }
    }
}

// ---------------- K3: sum fp16 partials -> (H*invN)@W_up + b_up -> gate -> out ----
__global__ __launch_bounds__(256) void k3_gate(
    const _Float16* __restrict__ HxPh, const _Float16* __restrict__ HyPh,
    const float* __restrict__ wup, const float* __restrict__ bup,
    const float* __restrict__ x, const float* __restrict__ y,
    float* __restrict__ out)
{
    const int b = blockIdx.y;
    const int t = threadIdx.x;
    const _Float16* part; const float* xin; float* outp; int L; float invN; int l0;
    int nq; long qstr;
    if (blockIdx.x < 4) {
        part = HxPh; nq = 64; qstr = (long)B_ * LX_ * 64;
        xin = x; outp = out; L = LX_; invN = 1.f / 1024.f; l0 = blockIdx.x * 32;
    } else {
        part = HyPh; nq = 8;  qstr = (long)B_ * LY_ * 64;
        xin = y; outp = out + (long)B_ * C_ * LX_; L = LY_; invN = 1.f / 128.f;
        l0 = (blockIdx.x - 4) * 32;
    }
    __shared__ float Ht[32][72];
    __shared__ float Wt[64][136];
    __shared__ float gg[32][133];

    const _Float16* p0 = part + ((long)b * L + l0) * 64;
    for (int u = t; u < 2048; u += 256) {
        float a0 = 0.f, a1 = 0.f, a2 = 0.f, a3 = 0.f;
        #pragma unroll 4
        for (int q = 0; q < nq; q += 4) {
            a0 += (float)p0[(long)q * qstr + u];
            a1 += (float)p0[(long)(q + 1) * qstr + u];
            a2 += (float)p0[(long)(q + 2) * qstr + u];
            a3 += (float)p0[(long)(q + 3) * qstr + u];
        }
        Ht[u >> 6][u & 63] = (a0 + a1) + (a2 + a3);
    }
    #pragma unroll
    for (int i = 0; i < 8; ++i) {
        int idx = t + i * 256;                 // 2048 float4 = 64x128 floats
        int r = idx >> 5, c4 = (idx & 31) * 4;
        *(float4*)&Wt[r][c4] = *(const float4*)(wup + idx * 4);
    }
    __syncthreads();

    const int lrow = t >> 3, cg = (t & 7) * 4;  // c = cg + 32*jj + i
    float acc[4][4];
    #pragma unroll
    for (int jj = 0; jj < 4; ++jj)
        #pragma unroll
        for (int i = 0; i < 4; ++i) acc[jj][i] = 0.f;
    #pragma unroll 4
    for (int k = 0; k < 64; ++k) {
        float hv = Ht[lrow][k];
        #pragma unroll
        for (int jj = 0; jj < 4; ++jj) {
            float4 wv = *(const float4*)&Wt[k][cg + 32 * jj];
            acc[jj][0] = fmaf(hv, wv.x, acc[jj][0]);
            acc[jj][1] = fmaf(hv, wv.y, acc[jj][1]);
            acc[jj][2] = fmaf(hv, wv.z, acc[jj][2]);
            acc[jj][3] = fmaf(hv, wv.w, acc[jj][3]);
        }
    }
    #pragma unroll
    for (int jj = 0; jj < 4; ++jj)
        #pragma unroll
        for (int i = 0; i < 4; ++i) {
            int c = cg + 32 * jj + i;
            float v = fmaf(acc[jj][i], invN, bup[c]);
            float sg = 1.f / (1.f + expf(-v));
            gg[lrow][c] = sg * tanhf(v);
        }
    __syncthreads();
    for (int u = t; u < 4096; u += 256) {
        int c = u >> 5, li = u & 31;
        long idx = ((long)b * C_ + c) * L + l0 + li;
        outp[idx] = xin[idx] * (0.5f + gg[li][c]);
    }
}

extern "C" void kernel_launch(void* const* d_in, const int* in_sizes, int n_in,
                              void* d_out, int out_size, void* d_ws, size_t ws_size,
                              hipStream_t stream) {
    (void)in_sizes; (void)n_in; (void)out_size; (void)ws_size;
    const float* x     = (const float*)d_in[0];
    const float* y     = (const float*)d_in[1];
    const float* Wdrug = (const float*)d_in[2];
    const float* bdrug = (const float*)d_in[3];
    const float* Wprot = (const float*)d_in[4];
    const float* bprot = (const float*)d_in[5];
    const float* Wdown = (const float*)d_in[6];
    const float* bdown = (const float*)d_in[7];
    const float* Wup   = (const float*)d_in[8];
    const float* bup   = (const float*)d_in[9];
    float* out = (float*)d_out;
    char* ws = (char*)d_ws;

    _Float16* datt = (_Float16*)ws;                 // 131072 halves  (256 KB)
    _Float16* patt = (_Float16*)(ws + 262144);      // 1048576 halves (2 MB)
    _Float16* wdTh = (_Float16*)(ws + 2359296);     // 8192 halves    (16 KB)
    _Float16* HxPh = (_Float16*)(ws + 2375680);     // 64 slabs x B*LX*64 fp16 (8 MB)
    _Float16* HyPh = (_Float16*)(ws + 10764288);    // 8 slabs x B*LY*64 fp16 (8 MB)

    hipLaunchKernelGGL(k1_att, dim3(2304), dim3(128), 0, stream,
                       x, y, Wdrug, bdrug, Wprot, bprot, Wdown, datt, patt, wdTh);
    hipLaunchKernelGGL(k2_main, dim3(1024), dim3(256), 0, stream,
                       datt, patt, wdTh, bdown, HxPh, HyPh);
    hipLaunchKernelGGL(k3_gate, dim3(36, 8), dim3(256), 0, stream,
                       HxPh, HyPh, Wup, bup, x, y, out);
}

// Round 20
// 62.971 us; speedup vs baseline: 1.2800x; 1.2800x over previous
//
#include <hip/hip_runtime.h>
#include <hip/hip_bf16.h>
#include <math.h>

#define B_  8
#define C_  128
#define CH_ 64
#define LX_ 128
#define LY_ 1024

typedef __attribute__((ext_vector_type(8)))  _Float16 half8;
typedef __attribute__((ext_vector_type(16))) float f32x16;

// ---------------- K1: att = x^T @ W + b -> fp16 ; blocks 0..63 also prep wdTh -----
// R20 change (only change this round): col stored TRANSPOSED col[c][0..3] so the
// inner loop does ONE uniform ds_read_b128 per c instead of 4x ds_read_b32.
// LDS ops/wave: 512 -> 129 (k1 is LDS-issue-bound: ~53K cyc/CU at the old layout).
__global__ __launch_bounds__(128) void k1_att(
    const float* __restrict__ x, const float* __restrict__ y,
    const float* __restrict__ Wd, const float* __restrict__ bd,
    const float* __restrict__ Wp, const float* __restrict__ bp,
    const float* __restrict__ Wdown,
    _Float16* __restrict__ datt, _Float16* __restrict__ patt,
    _Float16* __restrict__ wdTh)
{
    const int blk = blockIdx.x;
    const int t = threadIdx.x;
    if (blk < 64) {                        // wdTh[kh][c] = (fp16) W_down[c][kh]
        int u = blk * 128 + t;
        wdTh[u] = (_Float16)Wdown[(u & 127) * CH_ + (u >> 7)];
    }
    const float* src; const float* W; const float* bias; _Float16* dst; int L;
    int b, l0;
    if (blk < 256) {
        int row0 = blk * 4; b = row0 >> 7; l0 = row0 & 127;
        src = x; W = Wd; bias = bd; dst = datt; L = LX_;
    } else {
        int row0 = (blk - 256) * 4; b = row0 >> 10; l0 = row0 & 1023;
        src = y; W = Wp; bias = bp; dst = patt; L = LY_;
    }
    __shared__ float col[128][8];          // [c][l-quad], 32B rows (16B-aligned)
    {
        const float* sp = src + ((long)b * C_ + t) * L + l0;
        float4 v = *(const float4*)sp;
        *(float4*)&col[t][0] = v;          // one b128 write per thread
    }
    __syncthreads();
    float acc0 = bias[t], acc1 = acc0, acc2 = acc0, acc3 = acc0;
    #pragma unroll 8
    for (int c = 0; c < 128; ++c) {
        float w = W[c * 128 + t];
        float4 s = *(const float4*)&col[c][0];   // uniform broadcast b128
        acc0 = fmaf(s.x, w, acc0); acc1 = fmaf(s.y, w, acc1);
        acc2 = fmaf(s.z, w, acc2); acc3 = fmaf(s.w, w, acc3);
    }
    _Float16* dp = dst + ((long)b * L + l0) * C_ + t;
    dp[0]      = (_Float16)acc0; dp[C_]     = (_Float16)acc1;
    dp[2 * C_] = (_Float16)acc2; dp[3 * C_] = (_Float16)acc3;
}

// ---------------- K2: R18's kernel verbatim (best measured) -----------------------
// grid 1024, LB(256,4), LDS d-tile broadcast reads, no shfl/atomics, fp16 partials.
__global__ __launch_bounds__(256, 4) void k2_main(
    const _Float16* __restrict__ datt, const _Float16* __restrict__ patt,
    const _Float16* __restrict__ wdTh, const float* __restrict__ bdown,
    _Float16* __restrict__ HxPh, _Float16* __restrict__ HyPh)
{
    const int raw = blockIdx.x;
    const int bid = (raw & 7) * 128 + (raw >> 3);   // XCD-contiguous: share d-tiles
    const int lyblk = bid & 31;
    const int lxblk = (bid >> 5) & 3;
    const int b     = bid >> 7;
    const int t   = threadIdx.x;
    const int w   = t >> 6;
    const int wk  = w >> 1;             // kh half
    const int wl  = w & 1;              // lx half
    const int l   = t & 63;
    const int h   = l >> 5;             // k subgroup
    const int c32 = l & 31;             // ly row for A/pv; kh col for B/D

    __shared__ _Float16 dTh[32][136];     // 8.7 KB d-tile
    __shared__ float compWp[32][2][66];   // 16.9 KB [lx][h][kh] partials

    // ---- stage d-tile (coalesced: 512 half8 groups, contiguous) ----
    {
        const _Float16* dsrc = datt + ((long)(b * LX_) + lxblk * 32) * C_;
        #pragma unroll
        for (int i = 0; i < 2; ++i) {
            int idx = t + i * 256;
            *(half8*)&dTh[idx >> 4][(idx & 15) * 8] = *(const half8*)(dsrc + idx * 8);
        }
    }

    // ---- hoist p-fragments and B-fragments ----
    const _Float16* prow = patt + ((long)(b * LY_) + lyblk * 32 + c32) * C_ + h * 8;
    const _Float16* wrow = wdTh + (wk * 32 + c32) * C_ + h * 8;
    half8 pv[8], bf[8];
    #pragma unroll
    for (int kt = 0; kt < 8; ++kt) {
        pv[kt] = *(const half8*)(prow + kt * 16);
        bf[kt] = *(const half8*)(wrow + kt * 16);
    }
    const float bdr = bdown[wk * 32 + c32];
    const half8 hz = {};
    __syncthreads();

    float hy[16];
    #pragma unroll
    for (int r = 0; r < 16; ++r) hy[r] = 0.f;

    #pragma unroll 1
    for (int r = 0; r < 16; ++r) {
        const _Float16* dp = &dTh[wl * 16 + r][h * 8];
        f32x16 acc = {};
        #pragma unroll
        for (int kt = 0; kt < 8; ++kt) {
            half8 d = *(const half8*)(dp + kt * 16);            // LDS broadcast
            half8 s = __builtin_elementwise_max(d + pv[kt], hz);
            acc = __builtin_amdgcn_mfma_f32_32x32x16_f16(s, bf[kt], acc, 0, 0, 0);
        }
        // readout. D: col(kh)=wk*32+c32, row(ly)=(rr&3)+8*(rr>>2)+4h ; bias here
        float pa0 = 0.f, pa1 = 0.f, pa2 = 0.f, pa3 = 0.f;
        #pragma unroll
        for (int rr = 0; rr < 16; ++rr) {
            float v = fmaxf(acc[rr] + bdr, 0.f);
            hy[rr] += v;
            if      ((rr & 3) == 0) pa0 += v;
            else if ((rr & 3) == 1) pa1 += v;
            else if ((rr & 3) == 2) pa2 += v;
            else                    pa3 += v;
        }
        compWp[wl * 16 + r][h][wk * 32 + c32] = (pa0 + pa1) + (pa2 + pa3);
    }

    // ---- Hy -> exclusive fp16 slab (lxblk*2+wl), plain stores ----
    {
        _Float16* hyp = HyPh
            + (((long)(lxblk * 2 + wl) * B_ + b) * LY_ + lyblk * 32) * 64
            + wk * 32 + c32;
        #pragma unroll
        for (int rr = 0; rr < 16; ++rr) {
            int ly = (rr & 3) + 8 * (rr >> 2) + 4 * h;
            hyp[(long)ly * 64] = (_Float16)hy[rr];
        }
    }
    __syncthreads();

    // ---- Hx: combine h halves -> fp16 slab lyblk, coalesced ----
    {
        _Float16* hxp = HxPh + (((long)lyblk * B_ + b) * LX_ + lxblk * 32) * 64;
        for (int u = t; u < 2048; u += 256) {
            int r = u >> 6, c = u & 63;
            hxp[u] = (_Float16)(compWp[r][0][c] + compWp[r][1][c]);
        }
    }
}

// ---------------- K3: sum fp16 partials -> (H*invN)@W_up + b_up -> gate -> out ----
__global__ __launch_bounds__(256) void k3_gate(
    const _Float16* __restrict__ HxPh, const _Float16* __restrict__ HyPh,
    const float* __restrict__ wup, const float* __restrict__ bup,
    const float* __restrict__ x, const float* __restrict__ y,
    float* __restrict__ out)
{
    const int b = blockIdx.y;
    const int t = threadIdx.x;
    const _Float16* part; const float* xin; float* outp; int L; float invN; int l0;
    int nq; long qstr;
    if (blockIdx.x < 4) {
        part = HxPh; nq = 32; qstr = (long)B_ * LX_ * 64;
        xin = x; outp = out; L = LX_; invN = 1.f / 1024.f; l0 = blockIdx.x * 32;
    } else {
        part = HyPh; nq = 8;  qstr = (long)B_ * LY_ * 64;
        xin = y; outp = out + (long)B_ * C_ * LX_; L = LY_; invN = 1.f / 128.f;
        l0 = (blockIdx.x - 4) * 32;
    }
    __shared__ float Ht[32][72];
    __shared__ float Wt[64][136];
    __shared__ float gg[32][133];

    const _Float16* p0 = part + ((long)b * L + l0) * 64;
    for (int u = t; u < 2048; u += 256) {
        float a0 = 0.f, a1 = 0.f, a2 = 0.f, a3 = 0.f;
        #pragma unroll 4
        for (int q = 0; q < nq; q += 4) {
            a0 += (float)p0[(long)q * qstr + u];
            a1 += (float)p0[(long)(q + 1) * qstr + u];
            a2 += (float)p0[(long)(q + 2) * qstr + u];
            a3 += (float)p0[(long)(q + 3) * qstr + u];
        }
        Ht[u >> 6][u & 63] = (a0 + a1) + (a2 + a3);
    }
    #pragma unroll
    for (int i = 0; i < 8; ++i) {
        int idx = t + i * 256;                 // 2048 float4 = 64x128 floats
        int r = idx >> 5, c4 = (idx & 31) * 4;
        *(float4*)&Wt[r][c4] = *(const float4*)(wup + idx * 4);
    }
    __syncthreads();

    const int lrow = t >> 3, cg = (t & 7) * 4;  // c = cg + 32*jj + i
    float acc[4][4];
    #pragma unroll
    for (int jj = 0; jj < 4; ++jj)
        #pragma unroll
        for (int i = 0; i < 4; ++i) acc[jj][i] = 0.f;
    #pragma unroll 4
    for (int k = 0; k < 64; ++k) {
        float hv = Ht[lrow][k];
        #pragma unroll
        for (int jj = 0; jj < 4; ++jj) {
            float4 wv = *(const float4*)&Wt[k][cg + 32 * jj];
            acc[jj][0] = fmaf(hv, wv.x, acc[jj][0]);
            acc[jj][1] = fmaf(hv, wv.y, acc[jj][1]);
            acc[jj][2] = fmaf(hv, wv.z, acc[jj][2]);
            acc[jj][3] = fmaf(hv, wv.w, acc[jj][3]);
        }
    }
    #pragma unroll
    for (int jj = 0; jj < 4; ++jj)
        #pragma unroll
        for (int i = 0; i < 4; ++i) {
            int c = cg + 32 * jj + i;
            float v = fmaf(acc[jj][i], invN, bup[c]);
            float sg = 1.f / (1.f + expf(-v));
            gg[lrow][c] = sg * tanhf(v);
        }
    __syncthreads();
    for (int u = t; u < 4096; u += 256) {
        int c = u >> 5, li = u & 31;
        long idx = ((long)b * C_ + c) * L + l0 + li;
        outp[idx] = xin[idx] * (0.5f + gg[li][c]);
    }
}

extern "C" void kernel_launch(void* const* d_in, const int* in_sizes, int n_in,
                              void* d_out, int out_size, void* d_ws, size_t ws_size,
                              hipStream_t stream) {
    (void)in_sizes; (void)n_in; (void)out_size; (void)ws_size;
    const float* x     = (const float*)d_in[0];
    const float* y     = (const float*)d_in[1];
    const float* Wdrug = (const float*)d_in[2];
    const float* bdrug = (const float*)d_in[3];
    const float* Wprot = (const float*)d_in[4];
    const float* bprot = (const float*)d_in[5];
    const float* Wdown = (const float*)d_in[6];
    const float* bdown = (const float*)d_in[7];
    const float* Wup   = (const float*)d_in[8];
    const float* bup   = (const float*)d_in[9];
    float* out = (float*)d_out;
    char* ws = (char*)d_ws;

    _Float16* datt = (_Float16*)ws;                 // 131072 halves  (256 KB)
    _Float16* patt = (_Float16*)(ws + 262144);      // 1048576 halves (2 MB)
    _Float16* wdTh = (_Float16*)(ws + 2359296);     // 8192 halves    (16 KB)
    _Float16* HxPh = (_Float16*)(ws + 2375680);     // 32 slabs x B*LX*64 fp16 (4 MB)
    _Float16* HyPh = (_Float16*)(ws + 6569984);     // 8 slabs x B*LY*64 fp16 (8 MB)

    hipLaunchKernelGGL(k1_att, dim3(2304), dim3(128), 0, stream,
                       x, y, Wdrug, bdrug, Wprot, bprot, Wdown, datt, patt, wdTh);
    hipLaunchKernelGGL(k2_main, dim3(1024), dim3(256), 0, stream,
                       datt, patt, wdTh, bdown, HxPh, HyPh);
    hipLaunchKernelGGL(k3_gate, dim3(36, 8), dim3(256), 0, stream,
                       HxPh, HyPh, Wup, bup, x, y, out);
}

// Round 21
// 57.249 us; speedup vs baseline: 1.4079x; 1.0999x over previous
//
#include <hip/hip_runtime.h>
#include <hip/hip_bf16.h>
#include <math.h>

#define B_  8
#define C_  128
#define CH_ 64
#define LX_ 128
#define LY_ 1024

typedef __attribute__((ext_vector_type(8)))  _Float16 half8;
typedef __attribute__((ext_vector_type(16))) float f32x16;

// ---------------- K1: att = x^T @ W + b via MFMA (was VALU/LDS-bound) -------------
// grid (36, 8): lt<4 -> drug tile, else prot tile; 32 l-rows x 128 d per block.
// Stage x-tile transposed fp16 -> At[l][c]; W transposed fp16 -> Wt[d][c] (L2-hot).
// 4 waves x 8 MFMA 32x32x16 (same verified fragment pattern as k2). Blocks with
// b==0 && lt<32 also prep wdTh for k2.
__global__ __launch_bounds__(256) void k1_att(
    const float* __restrict__ x, const float* __restrict__ y,
    const float* __restrict__ Wd, const float* __restrict__ bd,
    const float* __restrict__ Wp, const float* __restrict__ bp,
    const float* __restrict__ Wdown,
    _Float16* __restrict__ datt, _Float16* __restrict__ patt,
    _Float16* __restrict__ wdTh)
{
    const int b  = blockIdx.y;
    const int lt = blockIdx.x;          // 0..35
    const int t  = threadIdx.x;
    if (b == 0 && lt < 32) {            // wdTh[kh][c] = (fp16) W_down[c][kh]
        int u = lt * 256 + t;
        wdTh[u] = (_Float16)Wdown[(u & 127) * CH_ + (u >> 7)];
    }
    const float* src; const float* W; const float* bias; _Float16* dst; int L; int l0;
    if (lt < 4) { src = x; W = Wd; bias = bd; dst = datt; L = LX_; l0 = lt * 32; }
    else        { src = y; W = Wp; bias = bp; dst = patt; L = LY_; l0 = (lt - 4) * 32; }

    __shared__ _Float16 At[32][136];    // A[l][c] = x[b][c][l0+l]  (8.7 KB)
    __shared__ _Float16 Wt[128][136];   // B^T[d][c] = W[c][d]      (34.8 KB)

    {   // stage A: coalesced 32-float rows of x, scatter-write transposed
        const float* xsrc = src + (long)b * C_ * L + l0;
        #pragma unroll
        for (int i = 0; i < 16; ++i) {
            int u = t + i * 256;        // 4096 elements
            int c = u >> 5, lq = u & 31;
            At[lq][c] = (_Float16)xsrc[(long)c * L + lq];
        }
        // stage W transposed (64 KB f32, L2-resident; coalesced reads)
        #pragma unroll
        for (int i = 0; i < 64; ++i) {
            int u = t + i * 256;        // 16384 elements
            int c = u >> 7, d = u & 127;
            Wt[d][c] = (_Float16)W[u];
        }
    }
    __syncthreads();

    const int w   = t >> 6;             // wave -> d0 = 32w
    const int l   = t & 63;
    const int h   = l >> 5;
    const int c32 = l & 31;
    const int d0  = w * 32;

    half8 af[8], bf[8];
    #pragma unroll
    for (int kt = 0; kt < 8; ++kt) {
        af[kt] = *(const half8*)&At[c32][kt * 16 + h * 8];
        bf[kt] = *(const half8*)&Wt[d0 + c32][kt * 16 + h * 8];
    }
    f32x16 acc = {};
    #pragma unroll
    for (int kt = 0; kt < 8; ++kt)
        acc = __builtin_amdgcn_mfma_f32_32x32x16_f16(af[kt], bf[kt], acc, 0, 0, 0);

    // D: col(d)=d0+c32, row(l)=(rr&3)+8*(rr>>2)+4h ; bias added here
    const float bv = bias[d0 + c32];
    _Float16* dp = dst + ((long)b * L + l0) * C_ + d0 + c32;
    #pragma unroll
    for (int rr = 0; rr < 16; ++rr) {
        int row = (rr & 3) + 8 * (rr >> 2) + 4 * h;
        dp[(long)row * C_] = (_Float16)(acc[rr] + bv);
    }
}

// ---------------- K2: R18/R20's kernel verbatim (best measured) -------------------
// grid 1024, LB(256,4), LDS d-tile broadcast reads, no shfl/atomics, fp16 partials.
__global__ __launch_bounds__(256, 4) void k2_main(
    const _Float16* __restrict__ datt, const _Float16* __restrict__ patt,
    const _Float16* __restrict__ wdTh, const float* __restrict__ bdown,
    _Float16* __restrict__ HxPh, _Float16* __restrict__ HyPh)
{
    const int raw = blockIdx.x;
    const int bid = (raw & 7) * 128 + (raw >> 3);   // XCD-contiguous: share d-tiles
    const int lyblk = bid & 31;
    const int lxblk = (bid >> 5) & 3;
    const int b     = bid >> 7;
    const int t   = threadIdx.x;
    const int w   = t >> 6;
    const int wk  = w >> 1;             // kh half
    const int wl  = w & 1;              // lx half
    const int l   = t & 63;
    const int h   = l >> 5;             // k subgroup
    const int c32 = l & 31;             // ly row for A/pv; kh col for B/D

    __shared__ _Float16 dTh[32][136];     // 8.7 KB d-tile
    __shared__ float compWp[32][2][66];   // 16.9 KB [lx][h][kh] partials

    // ---- stage d-tile (coalesced: 512 half8 groups, contiguous) ----
    {
        const _Float16* dsrc = datt + ((long)(b * LX_) + lxblk * 32) * C_;
        #pragma unroll
        for (int i = 0; i < 2; ++i) {
            int idx = t + i * 256;
            *(half8*)&dTh[idx >> 4][(idx & 15) * 8] = *(const half8*)(dsrc + idx * 8);
        }
    }

    // ---- hoist p-fragments and B-fragments ----
    const _Float16* prow = patt + ((long)(b * LY_) + lyblk * 32 + c32) * C_ + h * 8;
    const _Float16* wrow = wdTh + (wk * 32 + c32) * C_ + h * 8;
    half8 pv[8], bf[8];
    #pragma unroll
    for (int kt = 0; kt < 8; ++kt) {
        pv[kt] = *(const half8*)(prow + kt * 16);
        bf[kt] = *(const half8*)(wrow + kt * 16);
    }
    const float bdr = bdown[wk * 32 + c32];
    const half8 hz = {};
    __syncthreads();

    float hy[16];
    #pragma unroll
    for (int r = 0; r < 16; ++r) hy[r] = 0.f;

    #pragma unroll 1
    for (int r = 0; r < 16; ++r) {
        const _Float16* dp = &dTh[wl * 16 + r][h * 8];
        f32x16 acc = {};
        #pragma unroll
        for (int kt = 0; kt < 8; ++kt) {
            half8 d = *(const half8*)(dp + kt * 16);            // LDS broadcast
            half8 s = __builtin_elementwise_max(d + pv[kt], hz);
            acc = __builtin_amdgcn_mfma_f32_32x32x16_f16(s, bf[kt], acc, 0, 0, 0);
        }
        // readout. D: col(kh)=wk*32+c32, row(ly)=(rr&3)+8*(rr>>2)+4h ; bias here
        float pa0 = 0.f, pa1 = 0.f, pa2 = 0.f, pa3 = 0.f;
        #pragma unroll
        for (int rr = 0; rr < 16; ++rr) {
            float v = fmaxf(acc[rr] + bdr, 0.f);
            hy[rr] += v;
            if      ((rr & 3) == 0) pa0 += v;
            else if ((rr & 3) == 1) pa1 += v;
            else if ((rr & 3) == 2) pa2 += v;
            else                    pa3 += v;
        }
        compWp[wl * 16 + r][h][wk * 32 + c32] = (pa0 + pa1) + (pa2 + pa3);
    }

    // ---- Hy -> exclusive fp16 slab (lxblk*2+wl), plain stores ----
    {
        _Float16* hyp = HyPh
            + (((long)(lxblk * 2 + wl) * B_ + b) * LY_ + lyblk * 32) * 64
            + wk * 32 + c32;
        #pragma unroll
        for (int rr = 0; rr < 16; ++rr) {
            int ly = (rr & 3) + 8 * (rr >> 2) + 4 * h;
            hyp[(long)ly * 64] = (_Float16)hy[rr];
        }
    }
    __syncthreads();

    // ---- Hx: combine h halves -> fp16 slab lyblk, coalesced ----
    {
        _Float16* hxp = HxPh + (((long)lyblk * B_ + b) * LX_ + lxblk * 32) * 64;
        for (int u = t; u < 2048; u += 256) {
            int r = u >> 6, c = u & 63;
            hxp[u] = (_Float16)(compWp[r][0][c] + compWp[r][1][c]);
        }
    }
}

// ---------------- K3: sum fp16 partials -> (H*invN)@W_up + b_up -> gate -> out ----
__global__ __launch_bounds__(256) void k3_gate(
    const _Float16* __restrict__ HxPh, const _Float16* __restrict__ HyPh,
    const float* __restrict__ wup, const float* __restrict__ bup,
    const float* __restrict__ x, const float* __restrict__ y,
    float* __restrict__ out)
{
    const int b = blockIdx.y;
    const int t = threadIdx.x;
    const _Float16* part; const float* xin; float* outp; int L; float invN; int l0;
    int nq; long qstr;
    if (blockIdx.x < 4) {
        part = HxPh; nq = 32; qstr = (long)B_ * LX_ * 64;
        xin = x; outp = out; L = LX_; invN = 1.f / 1024.f; l0 = blockIdx.x * 32;
    } else {
        part = HyPh; nq = 8;  qstr = (long)B_ * LY_ * 64;
        xin = y; outp = out + (long)B_ * C_ * LX_; L = LY_; invN = 1.f / 128.f;
        l0 = (blockIdx.x - 4) * 32;
    }
    __shared__ float Ht[32][72];
    __shared__ float Wt[64][136];
    __shared__ float gg[32][133];

    const _Float16* p0 = part + ((long)b * L + l0) * 64;
    for (int u = t; u < 2048; u += 256) {
        float a0 = 0.f, a1 = 0.f, a2 = 0.f, a3 = 0.f;
        #pragma unroll 4
        for (int q = 0; q < nq; q += 4) {
            a0 += (float)p0[(long)q * qstr + u];
            a1 += (float)p0[(long)(q + 1) * qstr + u];
            a2 += (float)p0[(long)(q + 2) * qstr + u];
            a3 += (float)p0[(long)(q + 3) * qstr + u];
        }
        Ht[u >> 6][u & 63] = (a0 + a1) + (a2 + a3);
    }
    #pragma unroll
    for (int i = 0; i < 8; ++i) {
        int idx = t + i * 256;                 // 2048 float4 = 64x128 floats
        int r = idx >> 5, c4 = (idx & 31) * 4;
        *(float4*)&Wt[r][c4] = *(const float4*)(wup + idx * 4);
    }
    __syncthreads();

    const int lrow = t >> 3, cg = (t & 7) * 4;  // c = cg + 32*jj + i
    float acc[4][4];
    #pragma unroll
    for (int jj = 0; jj < 4; ++jj)
        #pragma unroll
        for (int i = 0; i < 4; ++i) acc[jj][i] = 0.f;
    #pragma unroll 4
    for (int k = 0; k < 64; ++k) {
        float hv = Ht[lrow][k];
        #pragma unroll
        for (int jj = 0; jj < 4; ++jj) {
            float4 wv = *(const float4*)&Wt[k][cg + 32 * jj];
            acc[jj][0] = fmaf(hv, wv.x, acc[jj][0]);
            acc[jj][1] = fmaf(hv, wv.y, acc[jj][1]);
            acc[jj][2] = fmaf(hv, wv.z, acc[jj][2]);
            acc[jj][3] = fmaf(hv, wv.w, acc[jj][3]);
        }
    }
    #pragma unroll
    for (int jj = 0; jj < 4; ++jj)
        #pragma unroll
        for (int i = 0; i < 4; ++i) {
            int c = cg + 32 * jj + i;
            float v = fmaf(acc[jj][i], invN, bup[c]);
            float sg = 1.f / (1.f + expf(-v));
            gg[lrow][c] = sg * tanhf(v);
        }
    __syncthreads();
    for (int u = t; u < 4096; u += 256) {
        int c = u >> 5, li = u & 31;
        long idx = ((long)b * C_ + c) * L + l0 + li;
        outp[idx] = xin[idx] * (0.5f + gg[li][c]);
    }
}

extern "C" void kernel_launch(void* const* d_in, const int* in_sizes, int n_in,
                              void* d_out, int out_size, void* d_ws, size_t ws_size,
                              hipStream_t stream) {
    (void)in_sizes; (void)n_in; (void)out_size; (void)ws_size;
    const float* x     = (const float*)d_in[0];
    const float* y     = (const float*)d_in[1];
    const float* Wdrug = (const float*)d_in[2];
    const float* bdrug = (const float*)d_in[3];
    const float* Wprot = (const float*)d_in[4];
    const float* bprot = (const float*)d_in[5];
    const float* Wdown = (const float*)d_in[6];
    const float* bdown = (const float*)d_in[7];
    const float* Wup   = (const float*)d_in[8];
    const float* bup   = (const float*)d_in[9];
    float* out = (float*)d_out;
    char* ws = (char*)d_ws;

    _Float16* datt = (_Float16*)ws;                 // 131072 halves  (256 KB)
    _Float16* patt = (_Float16*)(ws + 262144);      // 1048576 halves (2 MB)
    _Float16* wdTh = (_Float16*)(ws + 2359296);     // 8192 halves    (16 KB)
    _Float16* HxPh = (_Float16*)(ws + 2375680);     // 32 slabs x B*LX*64 fp16 (4 MB)
    _Float16* HyPh = (_Float16*)(ws + 6569984);     // 8 slabs x B*LY*64 fp16 (8 MB)

    hipLaunchKernelGGL(k1_att, dim3(36, 8), dim3(256), 0, stream,
                       x, y, Wdrug, bdrug, Wprot, bprot, Wdown, datt, patt, wdTh);
    hipLaunchKernelGGL(k2_main, dim3(1024), dim3(256), 0, stream,
                       datt, patt, wdTh, bdown, HxPh, HyPh);
    hipLaunchKernelGGL(k3_gate, dim3(36, 8), dim3(256), 0, stream,
                       HxPh, HyPh, Wup, bup, x, y, out);
}